// Round 6
// baseline (246.913 us; speedup 1.0000x reference)
//
#include <hip/hip_runtime.h>
#include <hip/hip_bf16.h>
#include <cstdint>
#include <cstddef>

#define NB   32
#define CIN  128
#define HWP  3136          // 56*56
#define KOC  256
#define NRS  9
#define PROW 3364          // 58*58 padded rows per (n,ck)
#define GUARD 256          // staging over-read guard rows at end of xt
#define AEL  24576         // elems per (ck,r) A slab = 3s*4w4*4i4*64lane*8e (48 KB)
#define BEL  12288         // elems per B window buffer = 384 rows * 32 (24 KB)

typedef __attribute__((ext_vector_type(8))) short  short8;
typedef __attribute__((ext_vector_type(4))) short  short4v;
typedef __attribute__((ext_vector_type(4))) float  float4v;

__device__ __forceinline__ unsigned short f2bf(float f) {
    union { float f; unsigned int u; } v; v.f = f;
    unsigned int u = v.u;
    u = u + 0x7fffu + ((u >> 16) & 1u);   // RNE
    return (unsigned short)(u >> 16);
}

// ---------------------------------------------------------------------------
// Fused prep kernel, three independent jobs (disjoint outputs, no ordering):
//   blocks [0, 1152):      W (OIHW fp32) -> wt2, layout
//                          [ck][r][s][w4][i4][quad][lr][e]
//                          (strides: ck 73728, r 24576, s 8192, w4 2048,
//                           i4 512, quad 128, lr 8, e 1)
//                          so each (ck,r) 48 KB A-slab (all 256 oc) stages
//                          LINEARLY into LDS via global_load_lds.
//   blocks [1152, 2816):   x NCHW fp32 -> xt[n][ck][p'][32c] bf16 halo layout
//   blocks [2816, 2930):   zero the 228 guard rows per (n,ck) slab
// ---------------------------------------------------------------------------
__global__ __launch_bounds__(256) void prep_kernel(const float* __restrict__ W,
                                                   unsigned short* __restrict__ wt2,
                                                   const float* __restrict__ x,
                                                   unsigned short* __restrict__ xt) {
    __shared__ unsigned short lds[32 * 260];
    int blk = blockIdx.x;
    int t   = threadIdx.x;

    if (blk < 1152) {
        // ---- wt2 part ----
        int idx  = blk * 256 + t;
        int e    = idx & 7;
        int lr   = (idx >> 3) & 15;
        int quad = (idx >> 7) & 3;
        int i4   = (idx >> 9) & 3;
        int w4   = (idx >> 11) & 3;
        int q13  = idx >> 13;          // ck*9 + r*3 + s, 0..35
        int s    = q13 % 3;
        int r    = (q13 / 3) % 3;
        int ck   = q13 / 9;
        int oc = w4 * 64 + i4 * 16 + lr;
        int c  = ck * 32 + quad * 8 + e;
        wt2[idx] = f2bf(W[((size_t)oc * CIN + c) * NRS + r * 3 + s]);
        return;
    }

    if (blk >= 2816) {
        // ---- guard-zero part: 128 slabs x 228 guard rows, 64 B each ----
        int g = (blk - 2816) * 256 + t;            // 0 .. 29183 (exact)
        int slab = g / 228;
        int gi   = g - slab * 228;
        int row;
        if (gi < 59)       row = gi;                               // top halo
        else if (gi < 169) { int k = gi - 59;                      // seam gaps
                             row = 115 + 58 * (k >> 1) + (k & 1); }
        else               row = 3305 + (gi - 169);                // bottom halo
        unsigned short* gr = xt + (size_t)slab * (PROW * 32) + (size_t)row * 32;
        short8 z = (short8)0;
        *(short8*)(gr +  0) = z;
        *(short8*)(gr +  8) = z;
        *(short8*)(gr + 16) = z;
        *(short8*)(gr + 24) = z;
        return;
    }

    // ---- xpose part (interior rows) ----
    int b    = blk - 1152;
    int tile = b % 13;
    int ck   = (b / 13) & 3;
    int n    = b / 52;
    int hw0  = tile * 256;
    int wv   = t >> 6;
    int lane = t & 63;

    const float* src = x + ((size_t)(n * CIN + ck * 32)) * HWP;
    #pragma unroll
    for (int pass = 0; pass < 8; ++pass) {
        int c  = pass * 4 + wv;
        int hw = hw0 + lane * 4;
        if (hw < HWP) {
            float4v v = *(const float4v*)(src + (size_t)c * HWP + hw);
            short4v s4;
            #pragma unroll
            for (int k = 0; k < 4; ++k) s4[k] = (short)f2bf(v[k]);
            *(short4v*)(&lds[c * 260 + lane * 4]) = s4;
        }
    }
    __syncthreads();

    int sub = t & 3;
    int hwl = t >> 2;
    unsigned short* dst = xt + ((size_t)(n * 4 + ck)) * PROW * 32;
    #pragma unroll
    for (int pass = 0; pass < 4; ++pass) {
        int hl = pass * 64 + hwl;
        int hw = hw0 + hl;
        if (hw < HWP) {
            short8 v;
            #pragma unroll
            for (int j = 0; j < 8; ++j)
                v[j] = (short)lds[(sub * 8 + j) * 260 + hl];
            int pr = hw + 59 + 2 * (hw / 56);
            *(short8*)(dst + (size_t)pr * 32 + sub * 8) = v;
        }
    }
}

// ---------------------------------------------------------------------------
// Stage one 48 KB A slab (one (ck,r): 3 taps x 256 oc x 32 ch) into LDS,
// linear (wt2 layout pre-arranged so fragment order == linear order).
// 8 waves x 6 instructions, 3072 x 16B chunks.
// ---------------------------------------------------------------------------
__device__ __forceinline__ void stage_A(const unsigned short* src,
                                        unsigned short* lbase,
                                        int wv, int lane) {
    #pragma unroll
    for (int it = 0; it < 6; ++it) {
        int c0 = it * 512 + wv * 64;       // wave-uniform chunk base
        __builtin_amdgcn_global_load_lds(
            (const __attribute__((address_space(1))) void*)(src + (size_t)(c0 + lane) * 8),
            (__attribute__((address_space(3))) void*)(lbase + (size_t)c0 * 8), 16, 0, 0);
    }
}

// ---------------------------------------------------------------------------
// Stage one 384-row halo window (24 KB) into LDS via async global_load_lds.
// XOR swizzle: LDS slot (r,q) holds global 16B-chunk (r, q ^ ((r>>1)&3)).
// 8 waves x 3 instructions cover all 1536 slots.
// ---------------------------------------------------------------------------
__device__ __forceinline__ void stage_B(const unsigned short* gwin,
                                        unsigned short* lbase,
                                        int wv, int lane) {
    #pragma unroll
    for (int it = 0; it < 3; ++it) {
        int blk = it * 8 + wv;             // wave-chunk 0..23 (wave-uniform)
        int s   = blk * 64 + lane;         // slot 0..1535
        int r   = s >> 2;
        int q   = s & 3;
        int qs  = q ^ ((r >> 1) & 3);
        __builtin_amdgcn_global_load_lds(
            (const __attribute__((address_space(1))) void*)(gwin + r * 32 + qs * 8),
            (__attribute__((address_space(3))) void*)(lbase + (size_t)blk * 512), 16, 0, 0);
    }
}

__device__ __forceinline__ short8 ldb(const char* lb, int r, int quad) {
    int q = quad ^ ((r >> 1) & 3);
    return *(const short8*)(lb + r * 64 + q * 16);
}

// ---------------------------------------------------------------------------
// Implicit GEMM, pure-LDS inner loop: 256 oc x 256 px per block, 512 threads
// (8 waves = 2 ocg x 4 wn), wave tile 128 oc x 64 px via 8x4
// mfma_f32_16x16x32_bf16 (acc[8][4] = 128 AGPR).
//
// Round-5 post-mortem: per-group wall 5619 cyc vs 2300 floor, IDENTICAL to
// round 4 despite 2 decoupled blocks/CU -> the wall is inside the group.
// Cause: wave tile 64x64 gives each B ds_read only 4 dependent MFMAs
// (77.6 cyc) < LDS latency (~120 cyc) -> built-in stall per j-step, and
// LDS-read cycles (2304/group) exceeded matrix cycles (1862) even at floor.
// This version raises the wave tile to 128x64: each B fragment feeds 8
// MFMAs (155 cyc > 120, self-covering), per-group matrix work doubles to
// 3725 cyc > LDS 3456 -> matrix-bound floor, and 12 barriers now amortize
// over 4x the FLOPs. LDS 144 KB (A 2x48 double-buf at (ck,r) + B 2x24 per
// ck) -> 1 block/CU, 8 waves. __launch_bounds__(512,2) -> 256-reg cap,
// ~195 live (acc 128 + af 32 + b 8 + addr), no spill.
// ---------------------------------------------------------------------------
__global__ __launch_bounds__(512, 2) void gemm_kernel(const unsigned short* __restrict__ xt,
                                                      const unsigned short* __restrict__ wt2,
                                                      const float* __restrict__ bias,
                                                      float* __restrict__ out) {
    __shared__ unsigned short lds[73728];  // 144 KB: A0@0 A1@24576 B0@49152 B1@61440

    int bx = blockIdx.x;                  // 13 pt x 32 n = 416
    int n  = bx & 31;
    int pt = bx >> 5;
    int p0 = pt * 256;

    int t    = threadIdx.x;
    int wv   = t >> 6;                    // 0..7
    int lane = t & 63;
    int lr   = lane & 15;
    int quad = lane >> 4;
    int ocg  = wv >> 2;                   // oc half (128 oc)
    int wn   = wv & 3;                    // px quarter (64 px)

    int prbase = p0 + 2 * (p0 / 56);      // = pr(p0) - 59, >= 0

    // per-j window row of the center tap (shift 0); clamped for tail tile
    int rb[4];
    #pragma unroll
    for (int j = 0; j < 4; ++j) {
        int hw  = p0 + wn * 64 + j * 16 + lr;
        int hwc = hw < HWP ? hw : (HWP - 1);
        rb[j] = hwc + 59 + 2 * (hwc / 56) - prbase;   // in [59, 325)
    }

    const unsigned short* xb = xt + (size_t)n * 4 * PROW * 32;

    float4v acc[8][4];
    #pragma unroll
    for (int i = 0; i < 8; ++i)
        #pragma unroll
        for (int j = 0; j < 4; ++j)
            acc[i][j] = (float4v){0.f, 0.f, 0.f, 0.f};

    // prologue: stage A(ck=0,r=0) -> A0, B(ck=0) -> B0
    stage_A(wt2, lds, wv, lane);
    stage_B(xb + (size_t)prbase * 32, lds + 49152, wv, lane);
    __syncthreads();

    for (int ck = 0; ck < 4; ++ck) {
        for (int r = 0; r < 3; ++r) {
            int g = ck * 3 + r;
            // issue next A slab into the alternate buffer (read of that
            // buffer finished at the barrier ending group g-1)
            if (g < 11) {
                int r2  = (r == 2) ? 0 : r + 1;
                int ck2 = (r == 2) ? ck + 1 : ck;
                stage_A(wt2 + (size_t)ck2 * 73728 + (size_t)r2 * AEL,
                        lds + ((g + 1) & 1) * AEL, wv, lane);
            }
            // issue next B window during the last tap-row of this ck
            if (r == 2 && ck < 3)
                stage_B(xb + (size_t)(ck + 1) * (PROW * 32) + (size_t)prbase * 32,
                        lds + 49152 + ((ck + 1) & 1) * BEL, wv, lane);

            const unsigned short* A = lds + (g & 1) * AEL + ocg * 4096 + lane * 8;
            const char* lbB = (const char*)(lds + 49152 + (ck & 1) * BEL);
            int sh0 = (r - 1) * 58;

            #pragma unroll
            for (int s = 0; s < 3; ++s) {
                int shift = sh0 + s - 1;           // = SH[r*3+s]
                short8 bcur = ldb(lbB, rb[0] + shift, quad);
                short8 af[8];
                #pragma unroll
                for (int i = 0; i < 8; ++i)
                    af[i] = *(const short8*)(A + s * 8192 + (i >> 2) * 2048 + (i & 3) * 512);
                __builtin_amdgcn_s_setprio(1);
                #pragma unroll
                for (int j = 0; j < 4; ++j) {
                    short8 bnext;
                    if (j < 3) bnext = ldb(lbB, rb[j + 1] + shift, quad);
                    #pragma unroll
                    for (int i = 0; i < 8; ++i)
                        acc[i][j] = __builtin_amdgcn_mfma_f32_16x16x32_bf16(
                            af[i], bcur, acc[i][j], 0, 0, 0);
                    if (j < 3) bcur = bnext;
                }
                __builtin_amdgcn_s_setprio(0);
            }
            __syncthreads();   // drains staging + all waves done with buffers
        }
    }

    // epilogue: D row = oc (quad*4+reg), col = pixel (lane&15)
    float* orow = out + (size_t)n * KOC * HWP;
    #pragma unroll
    for (int i = 0; i < 8; ++i) {
        #pragma unroll
        for (int rr = 0; rr < 4; ++rr) {
            int oc = ocg * 128 + i * 16 + quad * 4 + rr;
            float bi = bias[oc];
            #pragma unroll
            for (int j = 0; j < 4; ++j) {
                int hw = p0 + wn * 64 + j * 16 + lr;
                if (hw < HWP)
                    orow[(size_t)oc * HWP + hw] = acc[i][j][rr] + bi;
            }
        }
    }
}

// ---------------------------------------------------------------------------
// Safety fallback if ws is too small: naive direct conv (exact fp32).
// ---------------------------------------------------------------------------
__global__ void naive_kernel(const float* __restrict__ x, const float* __restrict__ W,
                             const float* __restrict__ b, float* __restrict__ out) {
    size_t idx = (size_t)blockIdx.x * 256 + threadIdx.x;
    if (idx >= (size_t)NB * KOC * HWP) return;
    int w0 = (int)(idx % 56);
    int h0 = (int)((idx / 56) % 56);
    int k  = (int)((idx / HWP) % KOC);
    int n  = (int)(idx / ((size_t)HWP * KOC));
    float acc = b[k];
    for (int c = 0; c < CIN; ++c) {
        const float* xr = x + ((size_t)n * CIN + c) * HWP;
        const float* wr = W + ((size_t)k * CIN + c) * NRS;
        for (int r = 0; r < 3; ++r) {
            int h = h0 + r - 1;
            if ((unsigned)h >= 56u) continue;
            for (int s = 0; s < 3; ++s) {
                int w = w0 + s - 1;
                if ((unsigned)w >= 56u) continue;
                acc += xr[h * 56 + w] * wr[r * 3 + s];
            }
        }
    }
    out[idx] = acc;
}

extern "C" void kernel_launch(void* const* d_in, const int* in_sizes, int n_in,
                              void* d_out, int out_size, void* d_ws, size_t ws_size,
                              hipStream_t stream) {
    const float* x  = (const float*)d_in[0];
    const float* W  = (const float*)d_in[1];
    const float* b  = (const float*)d_in[2];
    float* out = (float*)d_out;

    const size_t wt_elems = (size_t)NRS * 4 * 2 * 2 * 4 * 4 * 16 * 8;   // 294912
    const size_t xt_elems = (size_t)NB * 4 * PROW * 32 + (size_t)GUARD * 32;
    const size_t need = (wt_elems + xt_elems) * sizeof(unsigned short); // ~28.2 MB

    if (ws_size < need) {
        size_t total = (size_t)NB * KOC * HWP;
        naive_kernel<<<(unsigned)((total + 255) / 256), 256, 0, stream>>>(x, W, b, out);
        return;
    }

    unsigned short* wt2 = (unsigned short*)d_ws;
    unsigned short* xt  = wt2 + wt_elems;        // 16B-aligned

    // prep zeroes only the 228 guard rows per slab (no full-buffer memset)
    prep_kernel<<<1152 + NB * 4 * 13 + 114, 256, 0, stream>>>(W, wt2, x, xt);
    gemm_kernel<<<13 * 32, 512, 0, stream>>>(xt, wt2, b, out);
}

// Round 7
// 238.774 us; speedup vs baseline: 1.0341x; 1.0341x over previous
//
#include <hip/hip_runtime.h>
#include <hip/hip_bf16.h>
#include <cstdint>
#include <cstddef>

#define NB   32
#define CIN  128
#define HWP  3136          // 56*56
#define KOC  256
#define NRS  9
#define PROW 3364          // 58*58 padded rows per (n,ck)
#define GUARD 256          // staging over-read guard rows at end of xt
#define BEL  8192          // elems per B window buffer = 256 rows * 32 (16 KB)

typedef __attribute__((ext_vector_type(8))) short  short8;
typedef __attribute__((ext_vector_type(4))) short  short4v;
typedef __attribute__((ext_vector_type(4))) float  float4v;

__device__ __forceinline__ unsigned short f2bf(float f) {
    union { float f; unsigned int u; } v; v.f = f;
    unsigned int u = v.u;
    u = u + 0x7fffu + ((u >> 16) & 1u);   // RNE
    return (unsigned short)(u >> 16);
}

// ---------------------------------------------------------------------------
// Fused prep kernel, three independent jobs (disjoint outputs, no ordering):
//   blocks [0, 1152):      W (OIHW fp32) -> wt2, layout
//                          [ck][r][s][w4][i4][quad][lr][e]
//                          (strides: ck 73728, r 24576, s 8192, w4 2048,
//                           i4 512, quad 128, lr 8, e 1)
//                          -> one MFMA A fragment-set per (g=ck*3+r, s) is
//                          8192 elems, CONTIGUOUS, so the gemm kernel walks
//                          it with a single running offset.
//   blocks [1152, 2816):   x NCHW fp32 -> xt[n][ck][p'][32c] bf16 halo layout
//   blocks [2816, 2930):   zero the 228 guard rows per (n,ck) slab
// ---------------------------------------------------------------------------
__global__ __launch_bounds__(256) void prep_kernel(const float* __restrict__ W,
                                                   unsigned short* __restrict__ wt2,
                                                   const float* __restrict__ x,
                                                   unsigned short* __restrict__ xt) {
    __shared__ unsigned short lds[32 * 260];
    int blk = blockIdx.x;
    int t   = threadIdx.x;

    if (blk < 1152) {
        // ---- wt2 part ----
        int idx  = blk * 256 + t;
        int e    = idx & 7;
        int lr   = (idx >> 3) & 15;
        int quad = (idx >> 7) & 3;
        int i4   = (idx >> 9) & 3;
        int w4   = (idx >> 11) & 3;
        int q13  = idx >> 13;          // ck*9 + r*3 + s, 0..35
        int s    = q13 % 3;
        int r    = (q13 / 3) % 3;
        int ck   = q13 / 9;
        int oc = w4 * 64 + i4 * 16 + lr;
        int c  = ck * 32 + quad * 8 + e;
        wt2[idx] = f2bf(W[((size_t)oc * CIN + c) * NRS + r * 3 + s]);
        return;
    }

    if (blk >= 2816) {
        // ---- guard-zero part: 128 slabs x 228 guard rows, 64 B each ----
        int g = (blk - 2816) * 256 + t;            // 0 .. 29183 (exact)
        int slab = g / 228;
        int gi   = g - slab * 228;
        int row;
        if (gi < 59)       row = gi;                               // top halo
        else if (gi < 169) { int k = gi - 59;                      // seam gaps
                             row = 115 + 58 * (k >> 1) + (k & 1); }
        else               row = 3305 + (gi - 169);                // bottom halo
        unsigned short* gr = xt + (size_t)slab * (PROW * 32) + (size_t)row * 32;
        short8 z = (short8)0;
        *(short8*)(gr +  0) = z;
        *(short8*)(gr +  8) = z;
        *(short8*)(gr + 16) = z;
        *(short8*)(gr + 24) = z;
        return;
    }

    // ---- xpose part (interior rows) ----
    int b    = blk - 1152;
    int tile = b % 13;
    int ck   = (b / 13) & 3;
    int n    = b / 52;
    int hw0  = tile * 256;
    int wv   = t >> 6;
    int lane = t & 63;

    const float* src = x + ((size_t)(n * CIN + ck * 32)) * HWP;
    #pragma unroll
    for (int pass = 0; pass < 8; ++pass) {
        int c  = pass * 4 + wv;
        int hw = hw0 + lane * 4;
        if (hw < HWP) {
            float4v v = *(const float4v*)(src + (size_t)c * HWP + hw);
            short4v s4;
            #pragma unroll
            for (int k = 0; k < 4; ++k) s4[k] = (short)f2bf(v[k]);
            *(short4v*)(&lds[c * 260 + lane * 4]) = s4;
        }
    }
    __syncthreads();

    int sub = t & 3;
    int hwl = t >> 2;
    unsigned short* dst = xt + ((size_t)(n * 4 + ck)) * PROW * 32;
    #pragma unroll
    for (int pass = 0; pass < 4; ++pass) {
        int hl = pass * 64 + hwl;
        int hw = hw0 + hl;
        if (hw < HWP) {
            short8 v;
            #pragma unroll
            for (int j = 0; j < 8; ++j)
                v[j] = (short)lds[(sub * 8 + j) * 260 + hl];
            int pr = hw + 59 + 2 * (hw / 56);
            *(short8*)(dst + (size_t)pr * 32 + sub * 8) = v;
        }
    }
}

// ---------------------------------------------------------------------------
// Stage one 256-row halo window (16 KB) into LDS via async global_load_lds.
// XOR swizzle: LDS slot (r,q) holds global 16B-chunk (r, q ^ ((r>>1)&3)).
// 4 waves x 4 instructions cover all 1024 slots.
// ---------------------------------------------------------------------------
__device__ __forceinline__ void stage_B(const unsigned short* gwin,
                                        unsigned short* lbase,
                                        int wv, int lane) {
    #pragma unroll
    for (int it = 0; it < 4; ++it) {
        int blk = it * 4 + wv;             // wave-chunk 0..15 (wave-uniform)
        int s   = blk * 64 + lane;         // slot 0..1023
        int r   = s >> 2;
        int q   = s & 3;
        int qs  = q ^ ((r >> 1) & 3);
        __builtin_amdgcn_global_load_lds(
            (const __attribute__((address_space(1))) void*)(gwin + r * 32 + qs * 8),
            (__attribute__((address_space(3))) void*)(lbase + (size_t)blk * 512), 16, 0, 0);
    }
}

__device__ __forceinline__ short8 ldb(const char* lb, int r, int quad) {
    int q = quad ^ ((r >> 1) & 3);
    return *(const short8*)(lb + r * 64 + q * 16);
}

// ---------------------------------------------------------------------------
// Implicit GEMM: 128 oc x 128 px per block, 4 waves (2 oc x 2 px), wave tile
// 64x64 via 4x4 mfma_f32_16x16x32_bf16.
//
// Round-5/6 post-mortem: keeping A in LDS costs 48-96 KB (caps residency at
// 2 waves/SIMD) and half the LDS-port traffic; per-group wall stuck at
// ~5600 cyc (2.4x floor) because 2 waves/SIMD can't fill latency gaps, and
// the r6 rank-raise spilled (acc 128 + af > reg cap).
//
// This version: A NEVER touches LDS. Each wave holds af[12] (one group's
// 3 taps x 4 i-frags, 48 VGPR, statically indexed) and reloads each tap's
// 4 frags from global (L2-hot wt2, shared by all blocks) ONE TO TWO TAPS
// (~600-1200 cyc) before use:
//   tap s=0 loads af[8..11] <- this group's tap 2
//   tap s=1 loads af[0..3]  <- next group's tap 0
//   tap s=2 loads af[4..7]  <- next group's tap 1
// (prologue fills af[0..7]; the two tail loads at g=11 read harmless junk
// from the adjacent xt region, never consumed.)
// LDS = B halo windows only, 2 x 16 KB double-buffered per ck ->
// 3 blocks/CU (reg-gated), 3 waves/SIMD, and barriers drop from 12 to 4
// per block (only ck-boundary B swaps; register A needs no barriers).
// Regs: acc 64 AGPR + af 48 + bcur/bnext 8 + addr ~25 ~= 145 < 170 cap
// from __launch_bounds__(256,3) -> no spill (signature: WRITE == 100352 KB).
// B staging issued at END of ck body so per-tap A-load waits never sit
// behind the 16 KB DMA in the vmcnt queue (round-2 lesson).
// ---------------------------------------------------------------------------
__global__ __launch_bounds__(256, 3) void gemm_kernel(const unsigned short* __restrict__ xt,
                                                      const unsigned short* __restrict__ wt2,
                                                      const float* __restrict__ bias,
                                                      float* __restrict__ out) {
    __shared__ unsigned short lds[2 * BEL];   // 32 KB: B0@0 B1@8192

    int bx = blockIdx.x;                  // 25 pt x 32 n x 2 ot = 1600
    int ot = bx & 1;
    int n  = (bx >> 1) & 31;
    int pt = bx >> 6;
    int p0 = pt * 128;

    int t    = threadIdx.x;
    int wv   = t >> 6;                    // 0..3
    int lane = t & 63;
    int lr   = lane & 15;
    int quad = lane >> 4;
    int wm   = wv >> 1;                   // oc half (64 oc)
    int wn   = wv & 1;                    // px half (64 px)

    int prbase = p0 + 2 * (p0 / 56);      // = pr(p0) - 59, >= 0

    // per-j window row of the center tap (shift 0); clamped for tail tile
    int rb[4];
    #pragma unroll
    for (int j = 0; j < 4; ++j) {
        int hw  = p0 + wn * 64 + j * 16 + lr;
        int hwc = hw < HWP ? hw : (HWP - 1);
        rb[j] = hwc + 59 + 2 * (hwc / 56) - prbase;   // in [59, 193)
    }

    const unsigned short* xb = xt + (size_t)n * 4 * PROW * 32;
    // per-wave A base: w4 = ot*2+wm selects the 64-oc slice; lane*8 = quad*128+lr*8
    const unsigned short* ap = wt2 + (ot * 2 + wm) * 2048 + lane * 8;

    float4v acc[4][4];
    #pragma unroll
    for (int i = 0; i < 4; ++i)
        #pragma unroll
        for (int j = 0; j < 4; ++j)
            acc[i][j] = (float4v){0.f, 0.f, 0.f, 0.f};

    short8 af[12];

    // prologue: stage B(ck=0) -> B0; preload af[0..7] (g=0 taps 0,1)
    stage_B(xb + (size_t)prbase * 32, lds, wv, lane);
    #pragma unroll
    for (int k = 0; k < 8; ++k)
        af[k] = *(const short8*)(ap + (size_t)(k >> 2) * 8192 + (size_t)(k & 3) * 512);
    __syncthreads();

    for (int ck = 0; ck < 4; ++ck) {
        const char* lbB = (const char*)(lds + (ck & 1) * BEL);
        #pragma unroll
        for (int r = 0; r < 3; ++r) {
            const unsigned short* gb = ap + (size_t)(ck * 9 + r * 3) * 8192;
            int sh0 = (r - 1) * 58;

            #pragma unroll
            for (int s = 0; s < 3; ++s) {
                // A prefetch: dst regs 4*((s+2)%3), src tap (s+2) fwd of group base
                const int db = 4 * ((s + 2) % 3);
                #pragma unroll
                for (int i = 0; i < 4; ++i)
                    af[db + i] = *(const short8*)(gb + (size_t)(s + 2) * 8192
                                                     + (size_t)i * 512);
                int shift = sh0 + s - 1;
                short8 bcur = ldb(lbB, rb[0] + shift, quad);
                __builtin_amdgcn_s_setprio(1);
                #pragma unroll
                for (int j = 0; j < 4; ++j) {
                    short8 bnext;
                    if (j < 3) bnext = ldb(lbB, rb[j + 1] + shift, quad);
                    #pragma unroll
                    for (int i = 0; i < 4; ++i)
                        acc[i][j] = __builtin_amdgcn_mfma_f32_16x16x32_bf16(
                            af[4 * s + i], bcur, acc[i][j], 0, 0, 0);
                    if (j < 3) bcur = bnext;
                }
                __builtin_amdgcn_s_setprio(0);
            }
        }
        // stage-late: next ck's B window after all this ck's A-load issues
        if (ck < 3)
            stage_B(xb + (size_t)(ck + 1) * (PROW * 32) + (size_t)prbase * 32,
                    lds + ((ck + 1) & 1) * BEL, wv, lane);
        __syncthreads();   // drains staging; all waves done with B[ck&1]
    }

    // epilogue: D row = oc (quad*4+reg), col = pixel (lane&15)
    float* orow = out + (size_t)n * KOC * HWP;
    #pragma unroll
    for (int i = 0; i < 4; ++i) {
        #pragma unroll
        for (int rr = 0; rr < 4; ++rr) {
            int oc = ot * 128 + wm * 64 + i * 16 + quad * 4 + rr;
            float bi = bias[oc];
            #pragma unroll
            for (int j = 0; j < 4; ++j) {
                int hw = p0 + wn * 64 + j * 16 + lr;
                if (hw < HWP)
                    orow[(size_t)oc * HWP + hw] = acc[i][j][rr] + bi;
            }
        }
    }
}

// ---------------------------------------------------------------------------
// Safety fallback if ws is too small: naive direct conv (exact fp32).
// ---------------------------------------------------------------------------
__global__ void naive_kernel(const float* __restrict__ x, const float* __restrict__ W,
                             const float* __restrict__ b, float* __restrict__ out) {
    size_t idx = (size_t)blockIdx.x * 256 + threadIdx.x;
    if (idx >= (size_t)NB * KOC * HWP) return;
    int w0 = (int)(idx % 56);
    int h0 = (int)((idx / 56) % 56);
    int k  = (int)((idx / HWP) % KOC);
    int n  = (int)(idx / ((size_t)HWP * KOC));
    float acc = b[k];
    for (int c = 0; c < CIN; ++c) {
        const float* xr = x + ((size_t)n * CIN + c) * HWP;
        const float* wr = W + ((size_t)k * CIN + c) * NRS;
        for (int r = 0; r < 3; ++r) {
            int h = h0 + r - 1;
            if ((unsigned)h >= 56u) continue;
            for (int s = 0; s < 3; ++s) {
                int w = w0 + s - 1;
                if ((unsigned)w >= 56u) continue;
                acc += xr[h * 56 + w] * wr[r * 3 + s];
            }
        }
    }
    out[idx] = acc;
}

extern "C" void kernel_launch(void* const* d_in, const int* in_sizes, int n_in,
                              void* d_out, int out_size, void* d_ws, size_t ws_size,
                              hipStream_t stream) {
    const float* x  = (const float*)d_in[0];
    const float* W  = (const float*)d_in[1];
    const float* b  = (const float*)d_in[2];
    float* out = (float*)d_out;

    const size_t wt_elems = (size_t)NRS * 4 * 2 * 2 * 4 * 4 * 16 * 8;   // 294912
    const size_t xt_elems = (size_t)NB * 4 * PROW * 32 + (size_t)GUARD * 32;
    const size_t need = (wt_elems + xt_elems) * sizeof(unsigned short); // ~28.2 MB

    if (ws_size < need) {
        size_t total = (size_t)NB * KOC * HWP;
        naive_kernel<<<(unsigned)((total + 255) / 256), 256, 0, stream>>>(x, W, b, out);
        return;
    }

    unsigned short* wt2 = (unsigned short*)d_ws;
    unsigned short* xt  = wt2 + wt_elems;        // 16B-aligned

    // prep zeroes only the 228 guard rows per slab (no full-buffer memset)
    prep_kernel<<<1152 + NB * 4 * 13 + 114, 256, 0, stream>>>(W, wt2, x, xt);
    gemm_kernel<<<1600, 256, 0, stream>>>(xt, wt2, b, out);
}

// Round 8
// 196.036 us; speedup vs baseline: 1.2595x; 1.2180x over previous
//
#include <hip/hip_runtime.h>
#include <hip/hip_bf16.h>
#include <cstdint>
#include <cstddef>

#define NB   32
#define CIN  128
#define HWP  3136          // 56*56
#define KOC  256
#define NRS  9
#define PROW 3364          // 58*58 padded rows per (n,ck)
#define GUARD 256          // staging over-read guard rows at end of xt
#define AEL  12288         // elems per (ck,r,ot) A slab (24 KB)
#define BEL  8192          // elems per B window buffer = 256 rows * 32 (16 KB)

typedef __attribute__((ext_vector_type(8))) short  short8;
typedef __attribute__((ext_vector_type(4))) short  short4v;
typedef __attribute__((ext_vector_type(4))) float  float4v;

__device__ __forceinline__ unsigned short f2bf(float f) {
    union { float f; unsigned int u; } v; v.f = f;
    unsigned int u = v.u;
    u = u + 0x7fffu + ((u >> 16) & 1u);   // RNE
    return (unsigned short)(u >> 16);
}

// ---------------------------------------------------------------------------
// Fused prep kernel, three independent jobs (disjoint outputs, no ordering):
//   blocks [0, 1152):      W (OIHW fp32) -> wt2, layout
//                          [ck][r][ot][s][wm][i][quad][lr][e]
//                          (strides: ck 73728, r 24576, ot 12288, s 4096,
//                           wm 2048, i 512, quad 128, lr 8, e 1)
//                          so each (ck,r,ot) 24 KB A-slab stages LINEARLY
//                          into LDS via global_load_lds.
//   blocks [1152, 2816):   x NCHW fp32 -> xt[n][ck][p'][32c] bf16 halo layout
//   blocks [2816, 2930):   zero the 228 guard rows per (n,ck) slab
// ---------------------------------------------------------------------------
__global__ __launch_bounds__(256) void prep_kernel(const float* __restrict__ W,
                                                   unsigned short* __restrict__ wt2,
                                                   const float* __restrict__ x,
                                                   unsigned short* __restrict__ xt) {
    __shared__ unsigned short lds[32 * 260];
    int blk = blockIdx.x;
    int t   = threadIdx.x;

    if (blk < 1152) {
        // ---- wt2 part ----
        int idx  = blk * 256 + t;
        int e    = idx & 7;
        int lr   = (idx >> 3) & 15;
        int quad = (idx >> 7) & 3;
        int i    = (idx >> 9) & 3;
        int wm   = (idx >> 11) & 1;
        int rem  = idx >> 12;          // ck*18 + r*6 + ot*3 + s, 0..71
        int s    = rem % 3;
        int q    = rem / 3;            // ck*6 + r*2 + ot
        int ot   = q & 1;
        int r    = (q >> 1) % 3;
        int ck   = q / 6;
        int oc = ot * 128 + wm * 64 + i * 16 + lr;
        int c  = ck * 32 + quad * 8 + e;
        wt2[idx] = f2bf(W[((size_t)oc * CIN + c) * NRS + r * 3 + s]);
        return;
    }

    if (blk >= 2816) {
        // ---- guard-zero part: 128 slabs x 228 guard rows, 64 B each ----
        int g = (blk - 2816) * 256 + t;            // 0 .. 29183 (exact)
        int slab = g / 228;
        int gi   = g - slab * 228;
        int row;
        if (gi < 59)       row = gi;                               // top halo
        else if (gi < 169) { int k = gi - 59;                      // seam gaps
                             row = 115 + 58 * (k >> 1) + (k & 1); }
        else               row = 3305 + (gi - 169);                // bottom halo
        unsigned short* gr = xt + (size_t)slab * (PROW * 32) + (size_t)row * 32;
        short8 z = (short8)0;
        *(short8*)(gr +  0) = z;
        *(short8*)(gr +  8) = z;
        *(short8*)(gr + 16) = z;
        *(short8*)(gr + 24) = z;
        return;
    }

    // ---- xpose part (interior rows) ----
    int b    = blk - 1152;
    int tile = b % 13;
    int ck   = (b / 13) & 3;
    int n    = b / 52;
    int hw0  = tile * 256;
    int wv   = t >> 6;
    int lane = t & 63;

    const float* src = x + ((size_t)(n * CIN + ck * 32)) * HWP;
    #pragma unroll
    for (int pass = 0; pass < 8; ++pass) {
        int c  = pass * 4 + wv;
        int hw = hw0 + lane * 4;
        if (hw < HWP) {
            float4v v = *(const float4v*)(src + (size_t)c * HWP + hw);
            short4v s4;
            #pragma unroll
            for (int k = 0; k < 4; ++k) s4[k] = (short)f2bf(v[k]);
            *(short4v*)(&lds[c * 260 + lane * 4]) = s4;
        }
    }
    __syncthreads();

    int sub = t & 3;
    int hwl = t >> 2;
    unsigned short* dst = xt + ((size_t)(n * 4 + ck)) * PROW * 32;
    #pragma unroll
    for (int pass = 0; pass < 4; ++pass) {
        int hl = pass * 64 + hwl;
        int hw = hw0 + hl;
        if (hw < HWP) {
            short8 v;
            #pragma unroll
            for (int j = 0; j < 8; ++j)
                v[j] = (short)lds[(sub * 8 + j) * 260 + hl];
            int pr = hw + 59 + 2 * (hw / 56);
            *(short8*)(dst + (size_t)pr * 32 + sub * 8) = v;
        }
    }
}

// ---------------------------------------------------------------------------
// Stage one 24 KB A slab (one (ck,r,ot): 3 taps x 128 oc x 32 ch) into LDS,
// linear (wt2 layout pre-arranged so fragment order == linear order).
// 8 waves x 3 instructions, 1536 x 16B chunks.
// ---------------------------------------------------------------------------
__device__ __forceinline__ void stage_A(const unsigned short* src,
                                        unsigned short* lbase,
                                        int wv, int lane) {
    #pragma unroll
    for (int it = 0; it < 3; ++it) {
        int c0 = it * 512 + wv * 64;       // wave-uniform chunk base
        __builtin_amdgcn_global_load_lds(
            (const __attribute__((address_space(1))) void*)(src + (size_t)(c0 + lane) * 8),
            (__attribute__((address_space(3))) void*)(lbase + (size_t)c0 * 8), 16, 0, 0);
    }
}

// ---------------------------------------------------------------------------
// Stage one 256-row halo window (16 KB) into LDS via async global_load_lds.
// XOR swizzle: LDS slot (r,q) holds global 16B-chunk (r, q ^ ((r>>1)&3)).
// 8 waves x 2 instructions cover all 1024 slots.
// ---------------------------------------------------------------------------
__device__ __forceinline__ void stage_B(const unsigned short* gwin,
                                        unsigned short* lbase,
                                        int wv, int lane) {
    #pragma unroll
    for (int it = 0; it < 2; ++it) {
        int blk = it * 8 + wv;             // wave-chunk 0..15 (wave-uniform)
        int s   = blk * 64 + lane;         // slot 0..1023
        int r   = s >> 2;
        int q   = s & 3;
        int qs  = q ^ ((r >> 1) & 3);
        __builtin_amdgcn_global_load_lds(
            (const __attribute__((address_space(1))) void*)(gwin + r * 32 + qs * 8),
            (__attribute__((address_space(3))) void*)(lbase + (size_t)blk * 512), 16, 0, 0);
    }
}

__device__ __forceinline__ short8 ldb(const char* lb, int r, int quad) {
    int q = quad ^ ((r >> 1) & 3);
    return *(const short8*)(lb + r * 64 + q * 16);
}

// ---------------------------------------------------------------------------
// Implicit GEMM, pure-LDS inner loop (r5 structure, TLP-doubled):
// 128 oc x 128 px per block, 8 waves (2 oc-half x 4 px-quarter), wave tile
// 64 oc x 32 px via 4x2 mfma_f32_16x16x32_bf16 (acc[4][2] = 32 AGPR).
//
// r5 post-mortem: at 2 waves/SIMD the group wall was 2810 cyc/CU-instance
// vs floors of 931 (MFMA) / 1152 (LDS port) -- latency-bound, nothing
// saturated. Barrier decoupling (r4->r5) didn't move it; per-wave ILP
// raises (r6/r7) spilled. This version keeps r5's LDS plan (A dbuf 2x24 KB
// at (ck,r,ot) + B halo dbuf 2x16 KB = 80 KB -> 2 blocks/CU) but halves
// the wave tile so the block has 8 waves: 16 waves/CU = 4 waves/SIMD,
// double r5. Latency now hides via TLP. Registers: 32 acc + 16 af + 8 B
// + ~35 addr ~= 90 unified << 128 cap from __launch_bounds__(512,4)
// (margin ~38; every config within ~25 of its cap spilled: r1/r6/r7).
// No-spill signature: WRITE_SIZE == 100352 KB exactly.
//
// Bijective XCD-chunk swizzle (1600 % 8 == 0): each XCD gets a contiguous
// 200-block range, so the two ot-blocks sharing a B window and neighboring
// (pt,n) tiles hit the same per-XCD L2.
// ---------------------------------------------------------------------------
__global__ __launch_bounds__(512, 4) void gemm_kernel(const unsigned short* __restrict__ xt,
                                                      const unsigned short* __restrict__ wt2,
                                                      const float* __restrict__ bias,
                                                      float* __restrict__ out) {
    __shared__ unsigned short lds[40960];   // 80 KB: A0@0 A1@12288 B0@24576 B1@32768

    int bx0 = blockIdx.x;                 // 25 pt x 32 n x 2 ot = 1600
    int bx  = (bx0 & 7) * 200 + (bx0 >> 3);   // XCD chunk swizzle (bijective)
    int ot  = bx & 1;
    int n   = (bx >> 1) & 31;
    int pt  = bx >> 6;
    int p0  = pt * 128;

    int t    = threadIdx.x;
    int wv   = t >> 6;                    // 0..7
    int lane = t & 63;
    int lr   = lane & 15;
    int quad = lane >> 4;
    int wm   = wv >> 2;                   // oc half (64 oc)
    int wn   = wv & 3;                    // px quarter (32 px)

    int prbase = p0 + 2 * (p0 / 56);      // = pr(p0) - 59, >= 0

    // per-j window row of the center tap (shift 0); clamped for tail tile
    int rb[2];
    #pragma unroll
    for (int j = 0; j < 2; ++j) {
        int hw  = p0 + wn * 32 + j * 16 + lr;
        int hwc = hw < HWP ? hw : (HWP - 1);
        rb[j] = hwc + 59 + 2 * (hwc / 56) - prbase;   // in [59, 193)
    }

    const unsigned short* xb = xt + (size_t)n * 4 * PROW * 32;
    const unsigned short* wb = wt2 + ot * AEL;        // + ck*73728 + r*24576

    float4v acc[4][2];
    #pragma unroll
    for (int i = 0; i < 4; ++i)
        #pragma unroll
        for (int j = 0; j < 2; ++j)
            acc[i][j] = (float4v){0.f, 0.f, 0.f, 0.f};

    // prologue: stage A(ck=0,r=0) -> A0, B(ck=0) -> B0
    stage_A(wb, lds, wv, lane);
    stage_B(xb + (size_t)prbase * 32, lds + 24576, wv, lane);
    __syncthreads();

    for (int ck = 0; ck < 4; ++ck) {
        for (int r = 0; r < 3; ++r) {
            int g = ck * 3 + r;
            // issue next A slab into the alternate buffer (read of that
            // buffer finished at the barrier ending group g-1)
            if (g < 11) {
                int r2  = (r == 2) ? 0 : r + 1;
                int ck2 = (r == 2) ? ck + 1 : ck;
                stage_A(wb + (size_t)ck2 * 73728 + (size_t)r2 * 24576,
                        lds + ((g + 1) & 1) * AEL, wv, lane);
            }
            // issue next B window during the last tap-row of this ck
            if (r == 2 && ck < 3)
                stage_B(xb + (size_t)(ck + 1) * (PROW * 32) + (size_t)prbase * 32,
                        lds + 24576 + ((ck + 1) & 1) * BEL, wv, lane);

            const unsigned short* A = lds + (g & 1) * AEL + wm * 2048 + lane * 8;
            const char* lbB = (const char*)(lds + 24576 + (ck & 1) * BEL);
            int sh0 = (r - 1) * 58;

            #pragma unroll
            for (int s = 0; s < 3; ++s) {
                int shift = sh0 + s - 1;           // = SH[r*3+s]
                short8 af[4];
                #pragma unroll
                for (int i = 0; i < 4; ++i)
                    af[i] = *(const short8*)(A + s * 4096 + i * 512);
                short8 bcur = ldb(lbB, rb[0] + shift, quad);
                __builtin_amdgcn_s_setprio(1);
                #pragma unroll
                for (int j = 0; j < 2; ++j) {
                    short8 bnext;
                    if (j < 1) bnext = ldb(lbB, rb[j + 1] + shift, quad);
                    #pragma unroll
                    for (int i = 0; i < 4; ++i)
                        acc[i][j] = __builtin_amdgcn_mfma_f32_16x16x32_bf16(
                            af[i], bcur, acc[i][j], 0, 0, 0);
                    if (j < 1) bcur = bnext;
                }
                __builtin_amdgcn_s_setprio(0);
            }
            __syncthreads();   // drains staging + all waves done with buffers
        }
    }

    // epilogue: D row = oc (quad*4+reg), col = pixel (lane&15)
    float* orow = out + (size_t)n * KOC * HWP;
    #pragma unroll
    for (int i = 0; i < 4; ++i) {
        #pragma unroll
        for (int rr = 0; rr < 4; ++rr) {
            int oc = ot * 128 + wm * 64 + i * 16 + quad * 4 + rr;
            float bi = bias[oc];
            #pragma unroll
            for (int j = 0; j < 2; ++j) {
                int hw = p0 + wn * 32 + j * 16 + lr;
                if (hw < HWP)
                    orow[(size_t)oc * HWP + hw] = acc[i][j][rr] + bi;
            }
        }
    }
}

// ---------------------------------------------------------------------------
// Safety fallback if ws is too small: naive direct conv (exact fp32).
// ---------------------------------------------------------------------------
__global__ void naive_kernel(const float* __restrict__ x, const float* __restrict__ W,
                             const float* __restrict__ b, float* __restrict__ out) {
    size_t idx = (size_t)blockIdx.x * 256 + threadIdx.x;
    if (idx >= (size_t)NB * KOC * HWP) return;
    int w0 = (int)(idx % 56);
    int h0 = (int)((idx / 56) % 56);
    int k  = (int)((idx / HWP) % KOC);
    int n  = (int)(idx / ((size_t)HWP * KOC));
    float acc = b[k];
    for (int c = 0; c < CIN; ++c) {
        const float* xr = x + ((size_t)n * CIN + c) * HWP;
        const float* wr = W + ((size_t)k * CIN + c) * NRS;
        for (int r = 0; r < 3; ++r) {
            int h = h0 + r - 1;
            if ((unsigned)h >= 56u) continue;
            for (int s = 0; s < 3; ++s) {
                int w = w0 + s - 1;
                if ((unsigned)w >= 56u) continue;
                acc += xr[h * 56 + w] * wr[r * 3 + s];
            }
        }
    }
    out[idx] = acc;
}

extern "C" void kernel_launch(void* const* d_in, const int* in_sizes, int n_in,
                              void* d_out, int out_size, void* d_ws, size_t ws_size,
                              hipStream_t stream) {
    const float* x  = (const float*)d_in[0];
    const float* W  = (const float*)d_in[1];
    const float* b  = (const float*)d_in[2];
    float* out = (float*)d_out;

    const size_t wt_elems = (size_t)NRS * 4 * 2 * 2 * 4 * 4 * 16 * 8;   // 294912
    const size_t xt_elems = (size_t)NB * 4 * PROW * 32 + (size_t)GUARD * 32;
    const size_t need = (wt_elems + xt_elems) * sizeof(unsigned short); // ~28.2 MB

    if (ws_size < need) {
        size_t total = (size_t)NB * KOC * HWP;
        naive_kernel<<<(unsigned)((total + 255) / 256), 256, 0, stream>>>(x, W, b, out);
        return;
    }

    unsigned short* wt2 = (unsigned short*)d_ws;
    unsigned short* xt  = wt2 + wt_elems;        // 16B-aligned

    // prep zeroes only the 228 guard rows per slab (no full-buffer memset)
    prep_kernel<<<1152 + NB * 4 * 13 + 114, 256, 0, stream>>>(W, wt2, x, xt);
    gemm_kernel<<<1600, 512, 0, stream>>>(xt, wt2, b, out);
}